// Round 1
// baseline (830.074 us; speedup 1.0000x reference)
//
#include <hip/hip_runtime.h>
#include <hip/hip_bf16.h>

// Problem constants (fixed by the harness / reference setup_inputs()).
#define T_TOK   8192
#define D_MODEL 1024
#define DFF     4096
#define N_EXP   8
#define TOPK    2
#define CAP     2560
#define NASSIGN (T_TOK * TOPK)

typedef unsigned short u16;
typedef __attribute__((ext_vector_type(8))) short  short8;
typedef __attribute__((ext_vector_type(8))) unsigned short u16x8;
typedef __attribute__((ext_vector_type(4))) float  f32x4;

// ---------- helpers ----------

__device__ inline u16 f2bf(float f) {
    union { float f; unsigned u; } v; v.f = f;
    unsigned u = v.u;
    unsigned r = (u + 0x7fffu + ((u >> 16) & 1u)) >> 16;  // RNE
    return (u16)r;
}

__device__ inline float gelu_tanh(float x) {
    // jax.nn.gelu(approximate=True): 0.5*x*(1+tanh(sqrt(2/pi)*(x+0.044715 x^3)))
    float z = 0.7978845608028654f * (x + 0.044715f * x * x * x);
    z = fminf(fmaxf(z, -15.f), 15.f);
    float ez = __expf(2.f * z);
    float t = (ez - 1.f) / (ez + 1.f);
    return 0.5f * x * (1.f + t);
}

__device__ inline void gload_lds16(const void* g, void* l) {
    __builtin_amdgcn_global_load_lds(
        (const __attribute__((address_space(1))) unsigned int*)g,
        (__attribute__((address_space(3))) unsigned int*)l, 16, 0, 0);
}

// ---------- kernel 1: per-expert arrival-order scan ----------
// Block eb computes, for every assignment i with idx[i]==eb, its 0-based
// arrival rank; rank<CAP -> kept (pos_arr[i]=rank, slot_src[eb*CAP+rank]=token)
// else dropped (pos_arr[i]=-1). counts[eb] = min(total, CAP).
__global__ __launch_bounds__(256) void scan_kernel(
    const int* __restrict__ idx, int* __restrict__ counts,
    int* __restrict__ pos_arr, int* __restrict__ slot_src)
{
    const int eb = blockIdx.x;
    const int tid = threadIdx.x;
    __shared__ int sbuf[256];
    const int CHUNK = NASSIGN / 256;  // 64
    const int base_i = tid * CHUNK;
    int local = 0;
    #pragma unroll 8
    for (int j = 0; j < CHUNK; ++j) local += (idx[base_i + j] == eb) ? 1 : 0;
    sbuf[tid] = local;
    __syncthreads();
    for (int off = 1; off < 256; off <<= 1) {
        int v = (tid >= off) ? sbuf[tid - off] : 0;
        __syncthreads();
        sbuf[tid] += v;
        __syncthreads();
    }
    int run = sbuf[tid] - local;  // exclusive prefix
    for (int j = 0; j < CHUNK; ++j) {
        int i = base_i + j;
        if (idx[i] == eb) {
            if (run < CAP) { pos_arr[i] = run; slot_src[eb * CAP + run] = i / TOPK; }
            else           { pos_arr[i] = -1; }
            ++run;
        }
    }
    if (tid == 0) {
        int tot = sbuf[255];
        counts[eb] = tot < CAP ? tot : CAP;
    }
}

// ---------- kernel 2: transpose + f32->bf16 convert ----------
// in: [E][R][C] f32  ->  out: [E][C][R] bf16   (B^T layout for the GEMMs)
__global__ __launch_bounds__(256) void transpose_cvt(
    const float* __restrict__ in, u16* __restrict__ out, int R, int C)
{
    __shared__ float tile[32][33];
    const int e = blockIdx.z;
    const int c0 = blockIdx.x * 32, r0 = blockIdx.y * 32;
    const float* ine = in + (size_t)e * R * C;
    u16* oute = out + (size_t)e * R * C;
    const int tx = threadIdx.x, ty = threadIdx.y;  // (32, 8)
    #pragma unroll
    for (int i = 0; i < 4; ++i) {
        int r = ty + i * 8;
        tile[r][tx] = ine[(size_t)(r0 + r) * C + c0 + tx];
    }
    __syncthreads();
    #pragma unroll
    for (int i = 0; i < 4; ++i) {
        int cr = ty + i * 8;
        oute[(size_t)(c0 + cr) * R + r0 + tx] = f2bf(tile[tx][cr]);
    }
}

// ---------- kernel 3: gather tokens into per-expert bf16 buffers ----------
// Xe[e][slot][:] = bf16(x[slot_src[e,slot]][:]) for slot<cnt, else 0.
__global__ __launch_bounds__(128) void gather_kernel(
    const float* __restrict__ x, const int* __restrict__ counts,
    const int* __restrict__ slot_src, u16* __restrict__ Xe)
{
    const int b = blockIdx.x;
    const int e = b / CAP, slot = b % CAP;
    const int tid = threadIdx.x;
    u16* dst = Xe + ((size_t)e * CAP + slot) * D_MODEL + tid * 8;
    if (slot < counts[e]) {
        const int tok = slot_src[b];
        const float4* src = (const float4*)(x + (size_t)tok * D_MODEL) + tid * 2;
        float4 a = src[0], c = src[1];
        u16x8 v;
        v[0] = f2bf(a.x); v[1] = f2bf(a.y); v[2] = f2bf(a.z); v[3] = f2bf(a.w);
        v[4] = f2bf(c.x); v[5] = f2bf(c.y); v[6] = f2bf(c.z); v[7] = f2bf(c.w);
        *(u16x8*)dst = v;
    } else {
        float4 z = {0.f, 0.f, 0.f, 0.f};
        *(float4*)dst = z;
    }
}

// ---------- kernel 4/5: grouped GEMM (m97 structure) ----------
// C[e] = A[e] (rows x KD, bf16, row-major) @ Bt[e]^T (Bt is [ND][KD] bf16)
// 128x128 tile, BK=32, 4 waves each computing a 64x64 quadrant via 4x4
// mfma_f32_16x16x32_bf16 fragments; staging via global_load_lds width-16.
// FUSE_GELU: +bias, tanh-gelu, bf16 out. else: +bias, f32 out.
template<int KD, int ND, bool FUSE_GELU>
__global__ __launch_bounds__(256) void gemm_bt(
    const u16* __restrict__ A, const u16* __restrict__ Bt,
    const float* __restrict__ bias, void* __restrict__ Cout,
    const int* __restrict__ counts)
{
    const int e = blockIdx.z;
    const int brow = blockIdx.x * 128;
    if (brow >= counts[e]) return;  // rows beyond expert load are never read
    const int bcol = blockIdx.y * 128;

    const char* Ae = (const char*)(A + (size_t)e * CAP * KD + (size_t)brow * KD);
    const char* Be = (const char*)(Bt + (size_t)e * ND * KD + (size_t)bcol * KD);

    __shared__ __align__(16) u16 lsA[128 * 32];
    __shared__ __align__(16) u16 lsB[128 * 32];

    const int tid = threadIdx.x;
    const int lane = tid & 63;
    const int w = tid >> 6;
    const int wr = (w >> 1) * 64, wc = (w & 1) * 64;
    const int lr = lane & 15, lq = lane >> 4;

    f32x4 acc[4][4] = {};

    const size_t rstride = (size_t)KD * 2;        // bytes per row
    const char* ga0 = Ae + (size_t)(tid >> 2) * rstride + (size_t)(tid & 3) * 16;
    const char* gb0 = Be + (size_t)(tid >> 2) * rstride + (size_t)(tid & 3) * 16;
    char* la = (char*)lsA + tid * 16;
    char* lb = (char*)lsB + tid * 16;
    const size_t half = 64 * rstride;

    for (int kt = 0; kt < KD / 32; ++kt) {
        const size_t ko = (size_t)kt * 64;
        gload_lds16(ga0 + ko,        la);
        gload_lds16(ga0 + ko + half, la + 4096);
        gload_lds16(gb0 + ko,        lb);
        gload_lds16(gb0 + ko + half, lb + 4096);
        __syncthreads();
        short8 af[4], bfr[4];
        #pragma unroll
        for (int m = 0; m < 4; ++m)
            af[m] = *(const short8*)((const char*)lsA + ((wr + m * 16 + lr) * 64 + lq * 16));
        #pragma unroll
        for (int n = 0; n < 4; ++n)
            bfr[n] = *(const short8*)((const char*)lsB + ((wc + n * 16 + lr) * 64 + lq * 16));
        #pragma unroll
        for (int m = 0; m < 4; ++m)
            #pragma unroll
            for (int n = 0; n < 4; ++n)
                acc[m][n] = __builtin_amdgcn_mfma_f32_16x16x32_bf16(af[m], bfr[n], acc[m][n], 0, 0, 0);
        __syncthreads();
    }

    // epilogue: C/D map col=lane&15, row=(lane>>4)*4+reg  [m89/m91-verified]
    const float* be = bias + (size_t)e * ND + bcol;
    if (FUSE_GELU) {
        u16* Ce = (u16*)Cout + (size_t)e * CAP * ND + (size_t)brow * ND + bcol;
        #pragma unroll
        for (int m = 0; m < 4; ++m)
            #pragma unroll
            for (int n = 0; n < 4; ++n) {
                f32x4 v = acc[m][n];
                int c = wc + n * 16 + lr;
                float bb = be[c];
                #pragma unroll
                for (int j = 0; j < 4; ++j) {
                    int r = wr + m * 16 + lq * 4 + j;
                    Ce[(size_t)r * ND + c] = f2bf(gelu_tanh(v[j] + bb));
                }
            }
    } else {
        float* Ce = (float*)Cout + (size_t)e * CAP * ND + (size_t)brow * ND + bcol;
        #pragma unroll
        for (int m = 0; m < 4; ++m)
            #pragma unroll
            for (int n = 0; n < 4; ++n) {
                f32x4 v = acc[m][n];
                int c = wc + n * 16 + lr;
                float bb = be[c];
                #pragma unroll
                for (int j = 0; j < 4; ++j) {
                    int r = wr + m * 16 + lq * 4 + j;
                    Ce[(size_t)r * ND + c] = v[j] + bb;
                }
            }
    }
}

// ---------- kernel 6: weighted scatter-combine ----------
// out[t] = sum_k score[t,k] * keep * Y[e(t,k), pos(t,k)]
__global__ __launch_bounds__(256) void scatter_kernel(
    const int* __restrict__ idx, const float* __restrict__ scores,
    const int* __restrict__ pos_arr, const float* __restrict__ Y,
    float* __restrict__ out)
{
    const int t = blockIdx.x;
    const int tid = threadIdx.x;
    float4 acc = {0.f, 0.f, 0.f, 0.f};
    #pragma unroll
    for (int k = 0; k < TOPK; ++k) {
        int i = t * TOPK + k;
        int p = pos_arr[i];
        if (p >= 0) {
            int e = idx[i];
            float s = scores[i];
            float4 v = *(const float4*)(Y + ((size_t)e * CAP + p) * D_MODEL + tid * 4);
            acc.x += s * v.x; acc.y += s * v.y; acc.z += s * v.z; acc.w += s * v.w;
        }
    }
    *(float4*)(out + (size_t)t * D_MODEL + tid * 4) = acc;
}

// ---------- launcher ----------
extern "C" void kernel_launch(void* const* d_in, const int* in_sizes, int n_in,
                              void* d_out, int out_size, void* d_ws, size_t ws_size,
                              hipStream_t stream)
{
    const float* x      = (const float*)d_in[0];
    const int*   idx    = (const int*)d_in[1];
    const float* scores = (const float*)d_in[2];
    // d_in[3] = capacity scalar (compile-time CAP)
    const float* W1 = (const float*)d_in[4];
    const float* B1 = (const float*)d_in[5];
    const float* W2 = (const float*)d_in[6];
    const float* B2 = (const float*)d_in[7];
    float* out = (float*)d_out;

    char* ws = (char*)d_ws;
    size_t off = 0;
    auto alloc = [&](size_t bytes) {
        char* p = ws + off;
        off += (bytes + 255) & ~(size_t)255;
        return p;
    };
    int* counts   = (int*)alloc(N_EXP * 4);
    int* pos_arr  = (int*)alloc((size_t)NASSIGN * 4);
    int* slot_src = (int*)alloc((size_t)N_EXP * CAP * 4);
    u16* W1b = (u16*)alloc((size_t)N_EXP * D_MODEL * DFF * 2);   // 64 MiB
    u16* Xe  = (u16*)alloc((size_t)N_EXP * CAP * D_MODEL * 2);   // 40 MiB
    u16* W2b = (u16*)alloc((size_t)N_EXP * DFF * D_MODEL * 2);   // 64 MiB
    u16* H   = (u16*)alloc((size_t)N_EXP * CAP * DFF * 2);       // 160 MiB
    // Y (80 MiB f32) aliases W1b+Xe (104 MiB) — both dead when GEMM2 writes Y.
    float* Y = (float*)W1b;

    scan_kernel<<<N_EXP, 256, 0, stream>>>(idx, counts, pos_arr, slot_src);
    transpose_cvt<<<dim3(DFF / 32, D_MODEL / 32, N_EXP), dim3(32, 8), 0, stream>>>(
        W1, W1b, D_MODEL, DFF);
    transpose_cvt<<<dim3(D_MODEL / 32, DFF / 32, N_EXP), dim3(32, 8), 0, stream>>>(
        W2, W2b, DFF, D_MODEL);
    gather_kernel<<<N_EXP * CAP, 128, 0, stream>>>(x, counts, slot_src, Xe);
    gemm_bt<D_MODEL, DFF, true><<<dim3(CAP / 128, DFF / 128, N_EXP), 256, 0, stream>>>(
        Xe, W1b, B1, H, counts);
    gemm_bt<DFF, D_MODEL, false><<<dim3(CAP / 128, D_MODEL / 128, N_EXP), 256, 0, stream>>>(
        H, W2b, B2, Y, counts);
    scatter_kernel<<<T_TOK, 256, 0, stream>>>(idx, scores, pos_arr, Y, out);
}

// Round 2
// 795.707 us; speedup vs baseline: 1.0432x; 1.0432x over previous
//
#include <hip/hip_runtime.h>
#include <hip/hip_bf16.h>

// Problem constants (fixed by the harness / reference setup_inputs()).
#define T_TOK   8192
#define D_MODEL 1024
#define DFF     4096
#define N_EXP   8
#define TOPK    2
#define CAP     2560
#define NASSIGN (T_TOK * TOPK)

typedef unsigned short u16;
typedef __attribute__((ext_vector_type(8))) short  short8;
typedef __attribute__((ext_vector_type(8))) unsigned short u16x8;
typedef __attribute__((ext_vector_type(4))) float  f32x4;

// ---------- helpers ----------

__device__ inline u16 f2bf(float f) {
    union { float f; unsigned u; } v; v.f = f;
    unsigned u = v.u;
    unsigned r = (u + 0x7fffu + ((u >> 16) & 1u)) >> 16;  // RNE
    return (u16)r;
}

__device__ inline float gelu_tanh(float x) {
    float z = 0.7978845608028654f * (x + 0.044715f * x * x * x);
    z = fminf(fmaxf(z, -15.f), 15.f);
    float ez = __expf(2.f * z);
    float t = (ez - 1.f) / (ez + 1.f);
    return 0.5f * x * (1.f + t);
}

__device__ inline void gload_lds16(const void* g, void* l) {
    __builtin_amdgcn_global_load_lds(
        (const __attribute__((address_space(1))) unsigned int*)g,
        (__attribute__((address_space(3))) unsigned int*)l, 16, 0, 0);
}

__device__ __forceinline__ void BARm() {
    asm volatile("" ::: "memory");
    __builtin_amdgcn_sched_barrier(0);
    __builtin_amdgcn_s_barrier();
    __builtin_amdgcn_sched_barrier(0);
    asm volatile("" ::: "memory");
}

// ---------- kernel 1: per-expert arrival-order scan ----------
__global__ __launch_bounds__(256) void scan_kernel(
    const int* __restrict__ idx, int* __restrict__ counts,
    int* __restrict__ pos_arr, int* __restrict__ slot_src)
{
    const int eb = blockIdx.x;
    const int tid = threadIdx.x;
    __shared__ int sbuf[256];
    const int CHUNK = NASSIGN / 256;  // 64
    const int base_i = tid * CHUNK;
    int local = 0;
    #pragma unroll 8
    for (int j = 0; j < CHUNK; ++j) local += (idx[base_i + j] == eb) ? 1 : 0;
    sbuf[tid] = local;
    __syncthreads();
    for (int off = 1; off < 256; off <<= 1) {
        int v = (tid >= off) ? sbuf[tid - off] : 0;
        __syncthreads();
        sbuf[tid] += v;
        __syncthreads();
    }
    int run = sbuf[tid] - local;  // exclusive prefix
    for (int j = 0; j < CHUNK; ++j) {
        int i = base_i + j;
        if (idx[i] == eb) {
            if (run < CAP) { pos_arr[i] = run; slot_src[eb * CAP + run] = i / TOPK; }
            else           { pos_arr[i] = -1; }
            ++run;
        }
    }
    if (tid == 0) {
        int tot = sbuf[255];
        counts[eb] = tot < CAP ? tot : CAP;
    }
}

// ---------- kernel 2: transpose + f32->bf16 convert ----------
__global__ __launch_bounds__(256) void transpose_cvt(
    const float* __restrict__ in, u16* __restrict__ out, int R, int C)
{
    __shared__ float tile[32][33];
    const int e = blockIdx.z;
    const int c0 = blockIdx.x * 32, r0 = blockIdx.y * 32;
    const float* ine = in + (size_t)e * R * C;
    u16* oute = out + (size_t)e * R * C;
    const int tx = threadIdx.x, ty = threadIdx.y;  // (32, 8)
    #pragma unroll
    for (int i = 0; i < 4; ++i) {
        int r = ty + i * 8;
        tile[r][tx] = ine[(size_t)(r0 + r) * C + c0 + tx];
    }
    __syncthreads();
    #pragma unroll
    for (int i = 0; i < 4; ++i) {
        int cr = ty + i * 8;
        oute[(size_t)(c0 + cr) * R + r0 + tx] = f2bf(tile[tx][cr]);
    }
}

// ---------- kernel 3: gather tokens into per-expert bf16 buffers ----------
__global__ __launch_bounds__(128) void gather_kernel(
    const float* __restrict__ x, const int* __restrict__ counts,
    const int* __restrict__ slot_src, u16* __restrict__ Xe)
{
    const int b = blockIdx.x;
    const int e = b / CAP, slot = b % CAP;
    const int tid = threadIdx.x;
    u16* dst = Xe + ((size_t)e * CAP + slot) * D_MODEL + tid * 8;
    if (slot < counts[e]) {
        const int tok = slot_src[b];
        const float4* src = (const float4*)(x + (size_t)tok * D_MODEL) + tid * 2;
        float4 a = src[0], c = src[1];
        u16x8 v;
        v[0] = f2bf(a.x); v[1] = f2bf(a.y); v[2] = f2bf(a.z); v[3] = f2bf(a.w);
        v[4] = f2bf(c.x); v[5] = f2bf(c.y); v[6] = f2bf(c.z); v[7] = f2bf(c.w);
        *(u16x8*)dst = v;
    } else {
        float4 z = {0.f, 0.f, 0.f, 0.f};
        *(float4*)dst = z;
    }
}

// ---------- grouped GEMM: 256x256 tile, BK=64, 8-phase pipelined ----------
// A[e]: rows x KD bf16 row-major; Bt[e]: [ND][KD] bf16 (B^T).
// 8 waves as 2(M)x4(N); per-wave 128x64 output = 8x4 mfma_16x16x32 frags.
// LDS: 2 K-tile buffers, each 4 half-slots {AK0,AK1,BK0,BK1} of [256][32elem].
// Swizzle: in-row 16B-slot s' = s ^ ((row>>1)&3)  (2 lanes/bank on ds_read_b128).
// Staging: linear LDS dest + inverse-swizzled global source (involution).
// vmcnt(4) at K-tile boundaries (2 halves in flight), vmcnt(0) only entering
// the last tile. setprio(1) around each 16-MFMA cluster.
template<int KD, int ND, bool FUSE_GELU>
__global__ __launch_bounds__(512, 2) void gemm8(
    const u16* __restrict__ A, const u16* __restrict__ Bt,
    const float* __restrict__ bias, void* __restrict__ Cout,
    const int* __restrict__ counts, int nx, int ny)
{
    __shared__ __align__(16) char lds[131072];

    const int nwg = nx * ny * N_EXP;
    const int cpx = nwg >> 3;                 // nwg % 8 == 0 (bijective)
    const int id2 = (blockIdx.x & 7) * cpx + (blockIdx.x >> 3);
    const int e   = id2 / (nx * ny);
    const int rem = id2 % (nx * ny);
    const int bx = rem % nx, by = rem / nx;   // bx fastest: XCD chunk shares B-panel
    const int brow = bx << 8;
    if (brow >= counts[e]) return;
    const int bcol = by << 8;

    const int tid = threadIdx.x;
    const char* Ae = (const char*)(A + ((size_t)e * CAP + brow) * KD);
    const char* Be = (const char*)(Bt + ((size_t)e * ND + bcol) * KD);
    constexpr int RB = KD * 2;                // row bytes
    constexpr int NT = KD / 64;               // K-tiles (>=2 here)

    const int lane = tid & 63;
    const int wid = tid >> 6;
    const int wm = wid >> 2, wn = wid & 3;
    const int lr = lane & 15, lq = lane >> 4;

    const int srow0 = tid >> 2, ss = tid & 3; // staging: row=tid>>2, slot=tid&3

    // stage one half-slot (16 KiB): 2 x gload_lds(16B) per thread
    #define STG(gbase, buf, slot, kb) do {                                         \
        { int row_ = srow0;       int sl_ = ss ^ ((row_ >> 1) & 3);                \
          gload_lds16((gbase) + (size_t)row_ * RB + (kb) + sl_ * 16,               \
                      lds + (buf) * 65536 + (slot) * 16384 + tid * 16); }          \
        { int row_ = 128 + srow0; int sl_ = ss ^ ((row_ >> 1) & 3);                \
          gload_lds16((gbase) + (size_t)row_ * RB + (kb) + sl_ * 16,               \
                      lds + (buf) * 65536 + (slot) * 16384 + 8192 + tid * 16); }   \
    } while (0)

    // swizzled fragment read (16B)
    auto RD = [&](int buf, int slot, int row) -> short8 {
        int sl = lq ^ ((row >> 1) & 3);
        return *(const short8*)(lds + buf * 65536 + slot * 16384 + row * 64 + sl * 16);
    };

    f32x4 acc[8][4] = {};
    short8 af[4], bf[4];

    #define MFMA16(MB) do {                                                        \
        __builtin_amdgcn_s_setprio(1);                                             \
        _Pragma("unroll")                                                          \
        for (int m_ = 0; m_ < 4; ++m_)                                             \
            _Pragma("unroll")                                                      \
            for (int n_ = 0; n_ < 4; ++n_)                                         \
                acc[(MB) + m_][n_] = __builtin_amdgcn_mfma_f32_16x16x32_bf16(      \
                    af[m_], bf[n_], acc[(MB) + m_][n_], 0, 0, 0);                  \
        __builtin_amdgcn_s_setprio(0);                                             \
    } while (0)

    // ---- prologue: tile0 all 4 halves + tile1 {AK0,BK0}; wait first 4 halves
    STG(Ae, 0, 0, 0);        // AK0(0)
    STG(Be, 0, 2, 0);        // BK0(0)
    STG(Ae, 0, 1, 64);       // AK1(0)
    STG(Be, 0, 3, 64);       // BK1(0)
    STG(Ae, 1, 0, 128);      // AK0(1)
    STG(Be, 1, 2, 128);      // BK0(1)
    asm volatile("s_waitcnt vmcnt(4)" ::: "memory");
    BARm();

    for (int t = 0; t < NT; ++t) {
        const int buf = t & 1;
        const int obuf = buf ^ 1;

        // ---- phase 1: m0-3, ks0 ----
        #pragma unroll
        for (int n = 0; n < 4; ++n) bf[n] = RD(buf, 2, wn * 64 + n * 16 + lr);
        #pragma unroll
        for (int m = 0; m < 4; ++m) af[m] = RD(buf, 0, wm * 128 + m * 16 + lr);
        if (t + 1 < NT) STG(Ae, obuf, 1, (t + 1) * 128 + 64);   // AK1(t+1)
        BARm();
        MFMA16(0);
        BARm();

        // ---- phase 2: m4-7, ks0 ----
        #pragma unroll
        for (int m = 0; m < 4; ++m) af[m] = RD(buf, 0, wm * 128 + (4 + m) * 16 + lr);
        if (t + 1 < NT) STG(Be, obuf, 3, (t + 1) * 128 + 64);   // BK1(t+1)
        BARm();
        MFMA16(4);
        BARm();

        // ---- phase 3: m0-3, ks1 ----
        #pragma unroll
        for (int n = 0; n < 4; ++n) bf[n] = RD(buf, 3, wn * 64 + n * 16 + lr);
        #pragma unroll
        for (int m = 0; m < 4; ++m) af[m] = RD(buf, 1, wm * 128 + m * 16 + lr);
        if (t + 2 < NT) STG(Ae, buf, 0, (t + 2) * 128);         // AK0(t+2)
        BARm();
        MFMA16(0);
        BARm();

        // ---- phase 4: m4-7, ks1 + boundary wait ----
        #pragma unroll
        for (int m = 0; m < 4; ++m) af[m] = RD(buf, 1, wm * 128 + (4 + m) * 16 + lr);
        if (t + 2 < NT) STG(Be, buf, 2, (t + 2) * 128);         // BK0(t+2)
        BARm();
        MFMA16(4);
        if (t + 2 < NT)      { asm volatile("s_waitcnt vmcnt(4)" ::: "memory"); }
        else if (t + 1 < NT) { asm volatile("s_waitcnt vmcnt(0)" ::: "memory"); }
        BARm();
    }

    // ---- epilogue: C/D map col=lane&15, row=(lane>>4)*4+reg ----
    const float* be = bias + (size_t)e * ND + bcol;
    if (FUSE_GELU) {
        u16* Ce = (u16*)Cout + ((size_t)e * CAP + brow) * ND + bcol;
        #pragma unroll
        for (int m = 0; m < 8; ++m)
            #pragma unroll
            for (int n = 0; n < 4; ++n) {
                f32x4 v = acc[m][n];
                int c = wn * 64 + n * 16 + lr;
                float bb = be[c];
                #pragma unroll
                for (int j = 0; j < 4; ++j) {
                    int r = wm * 128 + m * 16 + lq * 4 + j;
                    Ce[(size_t)r * ND + c] = f2bf(gelu_tanh(v[j] + bb));
                }
            }
    } else {
        float* Ce = (float*)Cout + ((size_t)e * CAP + brow) * ND + bcol;
        #pragma unroll
        for (int m = 0; m < 8; ++m)
            #pragma unroll
            for (int n = 0; n < 4; ++n) {
                f32x4 v = acc[m][n];
                int c = wn * 64 + n * 16 + lr;
                float bb = be[c];
                #pragma unroll
                for (int j = 0; j < 4; ++j) {
                    int r = wm * 128 + m * 16 + lq * 4 + j;
                    Ce[(size_t)r * ND + c] = v[j] + bb;
                }
            }
    }
    #undef STG
    #undef MFMA16
}

// ---------- kernel 6: weighted scatter-combine ----------
__global__ __launch_bounds__(256) void scatter_kernel(
    const int* __restrict__ idx, const float* __restrict__ scores,
    const int* __restrict__ pos_arr, const float* __restrict__ Y,
    float* __restrict__ out)
{
    const int t = blockIdx.x;
    const int tid = threadIdx.x;
    float4 acc = {0.f, 0.f, 0.f, 0.f};
    #pragma unroll
    for (int k = 0; k < TOPK; ++k) {
        int i = t * TOPK + k;
        int p = pos_arr[i];
        if (p >= 0) {
            int e = idx[i];
            float s = scores[i];
            float4 v = *(const float4*)(Y + ((size_t)e * CAP + p) * D_MODEL + tid * 4);
            acc.x += s * v.x; acc.y += s * v.y; acc.z += s * v.z; acc.w += s * v.w;
        }
    }
    *(float4*)(out + (size_t)t * D_MODEL + tid * 4) = acc;
}

// ---------- launcher ----------
extern "C" void kernel_launch(void* const* d_in, const int* in_sizes, int n_in,
                              void* d_out, int out_size, void* d_ws, size_t ws_size,
                              hipStream_t stream)
{
    const float* x      = (const float*)d_in[0];
    const int*   idx    = (const int*)d_in[1];
    const float* scores = (const float*)d_in[2];
    // d_in[3] = capacity scalar (compile-time CAP)
    const float* W1 = (const float*)d_in[4];
    const float* B1 = (const float*)d_in[5];
    const float* W2 = (const float*)d_in[6];
    const float* B2 = (const float*)d_in[7];
    float* out = (float*)d_out;

    char* ws = (char*)d_ws;
    size_t off = 0;
    auto alloc = [&](size_t bytes) {
        char* p = ws + off;
        off += (bytes + 255) & ~(size_t)255;
        return p;
    };
    int* counts   = (int*)alloc(N_EXP * 4);
    int* pos_arr  = (int*)alloc((size_t)NASSIGN * 4);
    int* slot_src = (int*)alloc((size_t)N_EXP * CAP * 4);
    u16* W1b = (u16*)alloc((size_t)N_EXP * D_MODEL * DFF * 2);   // 64 MiB
    u16* Xe  = (u16*)alloc((size_t)N_EXP * CAP * D_MODEL * 2);   // 40 MiB
    u16* W2b = (u16*)alloc((size_t)N_EXP * DFF * D_MODEL * 2);   // 64 MiB
    u16* H   = (u16*)alloc((size_t)N_EXP * CAP * DFF * 2);       // 160 MiB
    // Y (80 MiB f32) aliases W1b+Xe (104 MiB) — both dead when GEMM2 writes Y.
    float* Y = (float*)W1b;

    scan_kernel<<<N_EXP, 256, 0, stream>>>(idx, counts, pos_arr, slot_src);
    transpose_cvt<<<dim3(DFF / 32, D_MODEL / 32, N_EXP), dim3(32, 8), 0, stream>>>(
        W1, W1b, D_MODEL, DFF);
    transpose_cvt<<<dim3(D_MODEL / 32, DFF / 32, N_EXP), dim3(32, 8), 0, stream>>>(
        W2, W2b, DFF, D_MODEL);
    gather_kernel<<<N_EXP * CAP, 128, 0, stream>>>(x, counts, slot_src, Xe);
    gemm8<D_MODEL, DFF, true><<<(CAP / 256) * (DFF / 256) * N_EXP, 512, 0, stream>>>(
        Xe, W1b, B1, H, counts, CAP / 256, DFF / 256);
    gemm8<DFF, D_MODEL, false><<<(CAP / 256) * (D_MODEL / 256) * N_EXP, 512, 0, stream>>>(
        H, W2b, B2, Y, counts, CAP / 256, D_MODEL / 256);
    scatter_kernel<<<T_TOK, 256, 0, stream>>>(idx, scores, pos_arr, Y, out);
}